// Round 3
// baseline (769.682 us; speedup 1.0000x reference)
//
#include <hip/hip_runtime.h>
#include <hip/hip_bf16.h>

// 2-layer GCN + mean pool. N=100000, E=1600000, G=128. dims 3 -> 64 -> 128.
//   h1  = relu( (A_hat x) @ W1 + b1 )        -- aggregate 3-dim x, then tiny GEMM
//   out = (mean_g (A_hat h1)) @ W2 + b2      -- aggregate 64-dim h1, pool, tiny GEMM
// A_hat row i = dinv[i] * ( sum_{e:dst=i} dinv[src]*v[src] + dinv[i]*v[i] )
// Rows are pre-scaled by dinv (xs, hs1) so gathers are pure unweighted sums.
//
// DTYPE-ADAPTIVE: previous rounds NaN'd; suspected cause = reading fp32 inputs
// as bf16 (random low-mantissa halves decode as bf16 NaNs). A device probe
// (k_detect) inspects raw bits of x and edge_index and sets flags in ws:
//   flags[0] = 1 if float tensors are bf16, 0 if fp32
//   flags[1] = 1 if index tensors are int64, 0 if int32
// Every kernel touching external data branches (wave-uniformly) on these.

typedef __hip_bfloat16 bf16;
#define NGRAPH 128

__device__ __forceinline__ float b2f(bf16 v) { return __bfloat162float(v); }

__device__ __forceinline__ float fld(const void* p, long long i, int isbf) {
    return isbf ? b2f(((const bf16*)p)[i]) : ((const float*)p)[i];
}
__device__ __forceinline__ int ild(const void* p, long long i, int is64) {
    return is64 ? (int)((const long long*)p)[i] : ((const int*)p)[i];
}

// ---- dtype probe --------------------------------------------------------
__global__ void k_detect(const void* x, const void* ei, int* flags) {
    if (threadIdx.x != 0 || blockIdx.x != 0) return;
    const unsigned short* u = (const unsigned short*)x;
    int good = 0;
    for (int k = 0; k < 128; ++k) {
        int e = (u[2 * k] >> 7) & 0xFF;       // exponent field if bf16
        if (e >= 90 && e <= 135) ++good;      // plausible for N(0,1) samples
    }
    flags[0] = (good >= 96) ? 1 : 0;          // bf16 mode
    const int* w = (const int*)ei;
    int zeros = 0;
    for (int k = 0; k < 64; ++k)
        if (w[2 * k + 1] == 0) ++zeros;       // int64 high words are all 0
    flags[1] = (zeros >= 56) ? 1 : 0;         // int64 mode
}

// ---- CSR build ----------------------------------------------------------
__global__ void k_deg(const void* __restrict__ ei, int* __restrict__ deg, int E,
                      const int* __restrict__ flags) {
    int e = blockIdx.x * blockDim.x + threadIdx.x;
    if (e >= E) return;
    int d = ild(ei, (long long)E + e, flags[1]);   // dst row
    atomicAdd(&deg[d], 1);
}

__global__ void k_counts(const void* __restrict__ batch, int* __restrict__ counts,
                         int n, const int* __restrict__ flags) {
    int i = blockIdx.x * blockDim.x + threadIdx.x;
    if (i < n) atomicAdd(&counts[ild(batch, i, flags[1])], 1);
}

__global__ void k_dinv(const int* __restrict__ deg, float* __restrict__ dinv, int n) {
    int i = blockIdx.x * blockDim.x + threadIdx.x;
    if (i < n) dinv[i] = rsqrtf((float)(deg[i] + 1));  // +1 self-loop; > 0 always
}

__global__ void k_scanA(const int* __restrict__ deg, int* __restrict__ row_ptr,
                        int* __restrict__ bsum, int n) {
    __shared__ int s[256];
    int i = blockIdx.x * 256 + threadIdx.x;
    int v = (i < n) ? deg[i] : 0;
    s[threadIdx.x] = v;
    __syncthreads();
    for (int d = 1; d < 256; d <<= 1) {
        int t = (threadIdx.x >= d) ? s[threadIdx.x - d] : 0;
        __syncthreads();
        s[threadIdx.x] += t;
        __syncthreads();
    }
    if (i < n) row_ptr[i] = s[threadIdx.x] - v;  // local exclusive
    if (threadIdx.x == 255) bsum[blockIdx.x] = s[255];
}

__global__ void k_scanB(int* __restrict__ bsum, int nb) {
    __shared__ int s[512];
    int v = (threadIdx.x < nb) ? bsum[threadIdx.x] : 0;
    s[threadIdx.x] = v;
    __syncthreads();
    for (int d = 1; d < 512; d <<= 1) {
        int t = (threadIdx.x >= d) ? s[threadIdx.x - d] : 0;
        __syncthreads();
        s[threadIdx.x] += t;
        __syncthreads();
    }
    if (threadIdx.x < nb) bsum[threadIdx.x] = s[threadIdx.x] - v;  // exclusive
}

__global__ void k_scanC(int* __restrict__ row_ptr, const int* __restrict__ bsum,
                        int n, int E) {
    int i = blockIdx.x * 256 + threadIdx.x;
    if (i < n) row_ptr[i] += bsum[i >> 8];
    if (i == 0) row_ptr[n] = E;
}

__global__ void k_fill(const void* __restrict__ ei, const int* __restrict__ row_ptr,
                       int* __restrict__ cursor, int* __restrict__ csr_src, int E,
                       const int* __restrict__ flags) {
    int e = blockIdx.x * blockDim.x + threadIdx.x;
    if (e >= E) return;
    int is64 = flags[1];
    int s = ild(ei, e, is64);
    int d = ild(ei, (long long)E + e, is64);
    int pos = row_ptr[d] + atomicAdd(&cursor[d], 1);
    csr_src[pos] = s;
}

// ---- layer 1 ------------------------------------------------------------
// xs[i] = dinv[i] * x[i]  (fp32, padded to float4)
__global__ void k_xs(const void* __restrict__ x, const float* __restrict__ dinv,
                     float4* __restrict__ xs, int n, const int* __restrict__ flags) {
    int i = blockIdx.x * blockDim.x + threadIdx.x;
    if (i >= n) return;
    int isbf = flags[0];
    float di = dinv[i];
    xs[i] = make_float4(di * fld(x, 3LL * i, isbf), di * fld(x, 3LL * i + 1, isbf),
                        di * fld(x, 3LL * i + 2, isbf), 0.0f);
}

// aggx[i] = dinv[i] * ( sum_{e:dst=i} xs[src_e] + xs[i] )   (= row i of A_hat x)
__global__ void k_gather1(const float4* __restrict__ xs, const float* __restrict__ dinv,
                          const int* __restrict__ row_ptr, const int* __restrict__ csr_src,
                          float4* __restrict__ aggx, int n) {
    int i = blockIdx.x * blockDim.x + threadIdx.x;
    if (i >= n) return;
    float4 a = xs[i];  // self loop
    int p1 = row_ptr[i + 1];
    for (int p = row_ptr[i]; p < p1; ++p) {
        float4 v = xs[csr_src[p]];
        a.x += v.x; a.y += v.y; a.z += v.z;
    }
    float di = dinv[i];
    aggx[i] = make_float4(di * a.x, di * a.y, di * a.z, 0.0f);
}

// hs1[i][j] = dinv[i] * relu( aggx[i] . W1[:,j] + b1[j] )   (stored bf16)
__global__ void k_h1(const float4* __restrict__ aggx, const float* __restrict__ dinv,
                     const void* __restrict__ W1, const void* __restrict__ b1,
                     bf16* __restrict__ hs1, int n, const int* __restrict__ flags) {
    __shared__ float w[256];  // [0..191]=W1 (3x64 row-major), [192..255]=b1
    int isbf = flags[0];
    if (threadIdx.x < 192) w[threadIdx.x] = fld(W1, threadIdx.x, isbf);
    if (threadIdx.x < 64) w[192 + threadIdx.x] = fld(b1, threadIdx.x, isbf);
    __syncthreads();
    long long t = (long long)blockIdx.x * 256 + threadIdx.x;
    int i = (int)(t >> 6), j = (int)(t & 63);
    if (i >= n) return;
    float4 a = aggx[i];
    float acc = a.x * w[j] + a.y * w[64 + j] + a.z * w[128 + j] + w[192 + j];
    hs1[(size_t)i * 64 + j] = __float2bfloat16(dinv[i] * fmaxf(acc, 0.0f));
}

// ---- layer 2 + pool -----------------------------------------------------
// P[g][j] += dinv[i] * ( sum_{e:dst=i} hs1[src][j] + hs1[i][j] )
__global__ void k_gather2(const bf16* __restrict__ hs1, const float* __restrict__ dinv,
                          const int* __restrict__ row_ptr, const int* __restrict__ csr_src,
                          const void* __restrict__ batch, float* __restrict__ P, int n,
                          const int* __restrict__ flags) {
    long long t = (long long)blockIdx.x * 256 + threadIdx.x;
    int i = (int)(t >> 6), j = (int)(t & 63);
    if (i >= n) return;
    float acc = b2f(hs1[(size_t)i * 64 + j]);  // self loop
    int p1 = row_ptr[i + 1];
    for (int p = row_ptr[i]; p < p1; ++p) {
        int s = csr_src[p];
        acc += b2f(hs1[(size_t)s * 64 + j]);
    }
    acc *= dinv[i];
    int g = ild(batch, i, flags[1]);
    atomicAdd(&P[g * 64 + j], acc);
}

// out[g][j] = (P[g]/count_g) . W2[:,j] + b2[j]   (0 if empty graph, per reference)
__global__ void k_out(const float* __restrict__ P, const int* __restrict__ counts,
                      const void* __restrict__ W2, const void* __restrict__ b2v,
                      void* __restrict__ out, const int* __restrict__ flags) {
    __shared__ float pm[64];
    int g = blockIdx.x, j = threadIdx.x;
    int isbf = flags[0];
    int c = counts[g];
    if (j < 64) pm[j] = (c > 0) ? P[g * 64 + j] / (float)c : 0.0f;
    __syncthreads();
    float acc = 0.0f;
    if (c > 0) {
        acc = fld(b2v, j, isbf);
        for (int k = 0; k < 64; ++k) acc += pm[k] * fld(W2, k * 128 + j, isbf);
    }
    if (isbf) ((bf16*)out)[g * 128 + j] = __float2bfloat16(acc);
    else      ((float*)out)[g * 128 + j] = acc;
}

extern "C" void kernel_launch(void* const* d_in, const int* in_sizes, int n_in,
                              void* d_out, int out_size, void* d_ws, size_t ws_size,
                              hipStream_t stream) {
    const void* x    = d_in[0];
    const void* ei   = d_in[1];   // edge_index [2,E] flat: src row then dst row
    const void* batch= d_in[2];
    const void* W1   = d_in[3];
    const void* b1   = d_in[4];
    const void* W2   = d_in[5];
    const void* b2   = d_in[6];

    const int N = in_sizes[0] / 3;
    const int E = in_sizes[1] / 2;

    // ---- workspace layout (512B aligned), total ~24 MB ----
    char* ws = (char*)d_ws;
    size_t off = 0;
    auto alloc = [&](size_t bytes) {
        size_t o = off;
        off = (off + bytes + 511) & ~(size_t)511;
        return o;
    };
    int* flags    = (int*)(ws + alloc(64 * 4));
    int* deg      = (int*)(ws + alloc((size_t)N * 4));
    float* dinv   = (float*)(ws + alloc((size_t)N * 4));
    int* row_ptr  = (int*)(ws + alloc((size_t)(N + 1) * 4));
    int* cursor   = (int*)(ws + alloc((size_t)N * 4));
    int* bsum     = (int*)(ws + alloc((size_t)512 * 4));
    int* csr_src  = (int*)(ws + alloc((size_t)E * 4));
    float4* xs    = (float4*)(ws + alloc((size_t)N * 16));
    float4* aggx  = (float4*)(ws + alloc((size_t)N * 16));
    bf16* hs1     = (bf16*)(ws + alloc((size_t)N * 64 * 2));
    float* P      = (float*)(ws + alloc((size_t)NGRAPH * 64 * 4));
    int* counts   = (int*)(ws + alloc((size_t)NGRAPH * 4));
    (void)ws_size;

    // zero atomic-accumulated regions (ws is re-poisoned 0xAA before each call)
    hipMemsetAsync(deg, 0, (size_t)N * 4, stream);
    hipMemsetAsync(cursor, 0, (size_t)N * 4, stream);
    hipMemsetAsync(P, 0, (size_t)NGRAPH * 64 * 4, stream);
    hipMemsetAsync(counts, 0, (size_t)NGRAPH * 4, stream);

    const int nb = (N + 255) / 256;        // 391
    const int eb = (E + 255) / 256;        // 6250
    const int fb = (N * 64 + 255) / 256;   // 25000

    k_detect<<<1, 64, 0, stream>>>(x, ei, flags);
    k_deg<<<eb, 256, 0, stream>>>(ei, deg, E, flags);
    k_counts<<<nb, 256, 0, stream>>>(batch, counts, N, flags);
    k_dinv<<<nb, 256, 0, stream>>>(deg, dinv, N);
    k_xs<<<nb, 256, 0, stream>>>(x, dinv, xs, N, flags);
    k_scanA<<<nb, 256, 0, stream>>>(deg, row_ptr, bsum, N);
    k_scanB<<<1, 512, 0, stream>>>(bsum, nb);
    k_scanC<<<nb, 256, 0, stream>>>(row_ptr, bsum, N, E);
    k_fill<<<eb, 256, 0, stream>>>(ei, row_ptr, cursor, csr_src, E, flags);
    k_gather1<<<nb, 256, 0, stream>>>(xs, dinv, row_ptr, csr_src, aggx, N);
    k_h1<<<fb, 256, 0, stream>>>(aggx, dinv, W1, b1, hs1, N, flags);
    k_gather2<<<fb, 256, 0, stream>>>(hs1, dinv, row_ptr, csr_src, batch, P, N, flags);
    k_out<<<NGRAPH, 128, 0, stream>>>(P, counts, W2, b2, d_out, flags);
}

// Round 4
// 485.849 us; speedup vs baseline: 1.5842x; 1.5842x over previous
//
#include <hip/hip_runtime.h>
#include <hip/hip_bf16.h>

// 2-layer GCN + mean pool. N=100000, E=1600000, G=128. dims 3 -> 64 -> 128.
//   h1  = relu( (A_hat x) @ W1 + b1 )        -- aggregate 3-dim x, then tiny GEMM
//   out = (mean_g (A_hat h1)) @ W2 + b2      -- aggregate 64-dim h1, pool, tiny GEMM
// A_hat row i = dinv[i] * ( sum_{e:dst=i} dinv[src]*v[src] + dinv[i]*v[i] )
// Rows are pre-scaled by dinv (xs, hs1) so gathers are pure unweighted sums.
//
// R3 -> R4: k_counts (273us, sorted-batch atomic contention) replaced by
// atomic-free boundary scan (batch is sorted). k_gather2 pool atomics cut 16x
// by wave-chunking (16 contiguous nodes/wave, register acc, flush on graph
// transition only).
//
// DTYPE-ADAPTIVE: device probe (k_detect) sets flags[0]=bf16?, flags[1]=int64?
// from raw bit patterns; all input-touching kernels branch wave-uniformly.

typedef __hip_bfloat16 bf16;
#define NGRAPH 128
#define CH 16   // nodes per wave in k_gather2

__device__ __forceinline__ float b2f(bf16 v) { return __bfloat162float(v); }

__device__ __forceinline__ float fld(const void* p, long long i, int isbf) {
    return isbf ? b2f(((const bf16*)p)[i]) : ((const float*)p)[i];
}
__device__ __forceinline__ int ild(const void* p, long long i, int is64) {
    return is64 ? (int)((const long long*)p)[i] : ((const int*)p)[i];
}

// ---- dtype probe --------------------------------------------------------
__global__ void k_detect(const void* x, const void* ei, int* flags) {
    if (threadIdx.x != 0 || blockIdx.x != 0) return;
    const unsigned short* u = (const unsigned short*)x;
    int good = 0;
    for (int k = 0; k < 128; ++k) {
        int e = (u[2 * k] >> 7) & 0xFF;       // exponent field if bf16
        if (e >= 90 && e <= 135) ++good;      // plausible for N(0,1) samples
    }
    flags[0] = (good >= 96) ? 1 : 0;          // bf16 mode
    const int* w = (const int*)ei;
    int zeros = 0;
    for (int k = 0; k < 64; ++k)
        if (w[2 * k + 1] == 0) ++zeros;       // int64 high words are all 0
    flags[1] = (zeros >= 56) ? 1 : 0;         // int64 mode
}

// ---- graph boundaries (batch is sorted; atomic-free) --------------------
// start[g] = first node index with batch >= g; start[NGRAPH] = n.
__global__ void k_bnd(const void* __restrict__ batch, int* __restrict__ start,
                      int n, const int* __restrict__ flags) {
    int i = blockIdx.x * blockDim.x + threadIdx.x;
    if (i >= n) return;
    int is64 = flags[1];
    int g = ild(batch, i, is64);
    int gp = (i == 0) ? -1 : ild(batch, i - 1, is64);
    for (int q = gp + 1; q <= g; ++q) start[q] = i;   // only boundary threads loop
    if (i == n - 1)
        for (int q = g + 1; q <= NGRAPH; ++q) start[q] = n;
}

// ---- CSR build ----------------------------------------------------------
__global__ void k_deg(const void* __restrict__ ei, int* __restrict__ deg, int E,
                      const int* __restrict__ flags) {
    int e = blockIdx.x * blockDim.x + threadIdx.x;
    if (e >= E) return;
    int d = ild(ei, (long long)E + e, flags[1]);   // dst row
    atomicAdd(&deg[d], 1);
}

__global__ void k_dinv(const int* __restrict__ deg, float* __restrict__ dinv, int n) {
    int i = blockIdx.x * blockDim.x + threadIdx.x;
    if (i < n) dinv[i] = rsqrtf((float)(deg[i] + 1));  // +1 self-loop; > 0 always
}

__global__ void k_scanA(const int* __restrict__ deg, int* __restrict__ row_ptr,
                        int* __restrict__ bsum, int n) {
    __shared__ int s[256];
    int i = blockIdx.x * 256 + threadIdx.x;
    int v = (i < n) ? deg[i] : 0;
    s[threadIdx.x] = v;
    __syncthreads();
    for (int d = 1; d < 256; d <<= 1) {
        int t = (threadIdx.x >= d) ? s[threadIdx.x - d] : 0;
        __syncthreads();
        s[threadIdx.x] += t;
        __syncthreads();
    }
    if (i < n) row_ptr[i] = s[threadIdx.x] - v;  // local exclusive
    if (threadIdx.x == 255) bsum[blockIdx.x] = s[255];
}

__global__ void k_scanB(int* __restrict__ bsum, int nb) {
    __shared__ int s[512];
    int v = (threadIdx.x < nb) ? bsum[threadIdx.x] : 0;
    s[threadIdx.x] = v;
    __syncthreads();
    for (int d = 1; d < 512; d <<= 1) {
        int t = (threadIdx.x >= d) ? s[threadIdx.x - d] : 0;
        __syncthreads();
        s[threadIdx.x] += t;
        __syncthreads();
    }
    if (threadIdx.x < nb) bsum[threadIdx.x] = s[threadIdx.x] - v;  // exclusive
}

__global__ void k_scanC(int* __restrict__ row_ptr, const int* __restrict__ bsum,
                        int n, int E) {
    int i = blockIdx.x * 256 + threadIdx.x;
    if (i < n) row_ptr[i] += bsum[i >> 8];
    if (i == 0) row_ptr[n] = E;
}

__global__ void k_fill(const void* __restrict__ ei, const int* __restrict__ row_ptr,
                       int* __restrict__ cursor, int* __restrict__ csr_src, int E,
                       const int* __restrict__ flags) {
    int e = blockIdx.x * blockDim.x + threadIdx.x;
    if (e >= E) return;
    int is64 = flags[1];
    int s = ild(ei, e, is64);
    int d = ild(ei, (long long)E + e, is64);
    int pos = row_ptr[d] + atomicAdd(&cursor[d], 1);
    csr_src[pos] = s;
}

// ---- layer 1 ------------------------------------------------------------
// xs[i] = dinv[i] * x[i]  (fp32, padded to float4)
__global__ void k_xs(const void* __restrict__ x, const float* __restrict__ dinv,
                     float4* __restrict__ xs, int n, const int* __restrict__ flags) {
    int i = blockIdx.x * blockDim.x + threadIdx.x;
    if (i >= n) return;
    int isbf = flags[0];
    float di = dinv[i];
    xs[i] = make_float4(di * fld(x, 3LL * i, isbf), di * fld(x, 3LL * i + 1, isbf),
                        di * fld(x, 3LL * i + 2, isbf), 0.0f);
}

// aggx[i] = dinv[i] * ( sum_{e:dst=i} xs[src_e] + xs[i] )   (= row i of A_hat x)
__global__ void k_gather1(const float4* __restrict__ xs, const float* __restrict__ dinv,
                          const int* __restrict__ row_ptr, const int* __restrict__ csr_src,
                          float4* __restrict__ aggx, int n) {
    int i = blockIdx.x * blockDim.x + threadIdx.x;
    if (i >= n) return;
    float4 a = xs[i];  // self loop
    int p1 = row_ptr[i + 1];
    for (int p = row_ptr[i]; p < p1; ++p) {
        float4 v = xs[csr_src[p]];
        a.x += v.x; a.y += v.y; a.z += v.z;
    }
    float di = dinv[i];
    aggx[i] = make_float4(di * a.x, di * a.y, di * a.z, 0.0f);
}

// hs1[i][j] = dinv[i] * relu( aggx[i] . W1[:,j] + b1[j] )   (stored bf16)
__global__ void k_h1(const float4* __restrict__ aggx, const float* __restrict__ dinv,
                     const void* __restrict__ W1, const void* __restrict__ b1,
                     bf16* __restrict__ hs1, int n, const int* __restrict__ flags) {
    __shared__ float w[256];  // [0..191]=W1 (3x64 row-major), [192..255]=b1
    int isbf = flags[0];
    if (threadIdx.x < 192) w[threadIdx.x] = fld(W1, threadIdx.x, isbf);
    if (threadIdx.x < 64) w[192 + threadIdx.x] = fld(b1, threadIdx.x, isbf);
    __syncthreads();
    long long t = (long long)blockIdx.x * 256 + threadIdx.x;
    int i = (int)(t >> 6), j = (int)(t & 63);
    if (i >= n) return;
    float4 a = aggx[i];
    float acc = a.x * w[j] + a.y * w[64 + j] + a.z * w[128 + j] + w[192 + j];
    hs1[(size_t)i * 64 + j] = __float2bfloat16(dinv[i] * fmaxf(acc, 0.0f));
}

// ---- layer 2 + pool -----------------------------------------------------
// One wave handles CH contiguous nodes (batch sorted => few graph transitions).
// Register acc per lane (feature j); flush to P[g][j] only on transition/end.
__global__ void k_gather2(const bf16* __restrict__ hs1, const float* __restrict__ dinv,
                          const int* __restrict__ row_ptr, const int* __restrict__ csr_src,
                          const void* __restrict__ batch, float* __restrict__ P, int n,
                          const int* __restrict__ flags) {
    int wid = (blockIdx.x * blockDim.x + threadIdx.x) >> 6;
    int j = threadIdx.x & 63;
    int i0 = wid * CH;
    if (i0 >= n) return;
    int i1 = min(i0 + CH, n);
    int is64 = flags[1];
    float acc = 0.0f;
    int gcur = ild(batch, i0, is64);
    for (int i = i0; i < i1; ++i) {
        int g = ild(batch, i, is64);
        if (g != gcur) {
            atomicAdd(&P[gcur * 64 + j], acc);
            acc = 0.0f;
            gcur = g;
        }
        float a = b2f(hs1[(size_t)i * 64 + j]);  // self loop
        int p1 = row_ptr[i + 1];
        for (int p = row_ptr[i]; p < p1; ++p)
            a += b2f(hs1[(size_t)csr_src[p] * 64 + j]);
        acc += a * dinv[i];
    }
    atomicAdd(&P[gcur * 64 + j], acc);
}

// out[g][j] = (P[g]/count_g) . W2[:,j] + b2[j]   (0 if empty graph, per reference)
__global__ void k_out(const float* __restrict__ P, const int* __restrict__ start,
                      const void* __restrict__ W2, const void* __restrict__ b2v,
                      void* __restrict__ out, const int* __restrict__ flags) {
    __shared__ float pm[64];
    int g = blockIdx.x, j = threadIdx.x;
    int isbf = flags[0];
    int c = start[g + 1] - start[g];
    if (j < 64) pm[j] = (c > 0) ? P[g * 64 + j] / (float)c : 0.0f;
    __syncthreads();
    float acc = 0.0f;
    if (c > 0) {
        acc = fld(b2v, j, isbf);
        for (int k = 0; k < 64; ++k) acc += pm[k] * fld(W2, k * 128 + j, isbf);
    }
    if (isbf) ((bf16*)out)[g * 128 + j] = __float2bfloat16(acc);
    else      ((float*)out)[g * 128 + j] = acc;
}

extern "C" void kernel_launch(void* const* d_in, const int* in_sizes, int n_in,
                              void* d_out, int out_size, void* d_ws, size_t ws_size,
                              hipStream_t stream) {
    const void* x    = d_in[0];
    const void* ei   = d_in[1];   // edge_index [2,E] flat: src row then dst row
    const void* batch= d_in[2];
    const void* W1   = d_in[3];
    const void* b1   = d_in[4];
    const void* W2   = d_in[5];
    const void* b2   = d_in[6];

    const int N = in_sizes[0] / 3;
    const int E = in_sizes[1] / 2;

    // ---- workspace layout (512B aligned), total ~24 MB ----
    char* ws = (char*)d_ws;
    size_t off = 0;
    auto alloc = [&](size_t bytes) {
        size_t o = off;
        off = (off + bytes + 511) & ~(size_t)511;
        return o;
    };
    int* flags    = (int*)(ws + alloc(64 * 4));
    int* deg      = (int*)(ws + alloc((size_t)N * 4));
    float* dinv   = (float*)(ws + alloc((size_t)N * 4));
    int* row_ptr  = (int*)(ws + alloc((size_t)(N + 1) * 4));
    int* cursor   = (int*)(ws + alloc((size_t)N * 4));
    int* bsum     = (int*)(ws + alloc((size_t)512 * 4));
    int* start    = (int*)(ws + alloc((size_t)(NGRAPH + 1) * 4));
    int* csr_src  = (int*)(ws + alloc((size_t)E * 4));
    float4* xs    = (float4*)(ws + alloc((size_t)N * 16));
    float4* aggx  = (float4*)(ws + alloc((size_t)N * 16));
    bf16* hs1     = (bf16*)(ws + alloc((size_t)N * 64 * 2));
    float* P      = (float*)(ws + alloc((size_t)NGRAPH * 64 * 4));
    (void)ws_size;

    // zero atomic-accumulated regions (ws is re-poisoned 0xAA before each call)
    hipMemsetAsync(deg, 0, (size_t)N * 4, stream);
    hipMemsetAsync(cursor, 0, (size_t)N * 4, stream);
    hipMemsetAsync(P, 0, (size_t)NGRAPH * 64 * 4, stream);

    const int nb = (N + 255) / 256;        // 391
    const int eb = (E + 255) / 256;        // 6250
    const int fb = (N * 64 + 255) / 256;   // 25000
    const int gb = ((N + CH - 1) / CH * 64 + 255) / 256;  // gather2 blocks

    k_detect<<<1, 64, 0, stream>>>(x, ei, flags);
    k_bnd<<<nb, 256, 0, stream>>>(batch, start, N, flags);
    k_deg<<<eb, 256, 0, stream>>>(ei, deg, E, flags);
    k_dinv<<<nb, 256, 0, stream>>>(deg, dinv, N);
    k_xs<<<nb, 256, 0, stream>>>(x, dinv, xs, N, flags);
    k_scanA<<<nb, 256, 0, stream>>>(deg, row_ptr, bsum, N);
    k_scanB<<<1, 512, 0, stream>>>(bsum, nb);
    k_scanC<<<nb, 256, 0, stream>>>(row_ptr, bsum, N, E);
    k_fill<<<eb, 256, 0, stream>>>(ei, row_ptr, cursor, csr_src, E, flags);
    k_gather1<<<nb, 256, 0, stream>>>(xs, dinv, row_ptr, csr_src, aggx, N);
    k_h1<<<fb, 256, 0, stream>>>(aggx, dinv, W1, b1, hs1, N, flags);
    k_gather2<<<gb, 256, 0, stream>>>(hs1, dinv, row_ptr, csr_src, batch, P, N, flags);
    k_out<<<NGRAPH, 128, 0, stream>>>(P, start, W2, b2, d_out, flags);
}